// Round 2
// baseline (414.085 us; speedup 1.0000x reference)
//
#include <hip/hip_runtime.h>
#include <hip/hip_bf16.h>
#include <math.h>

#define SEQ   2048
#define EMBED 2048
#define NHEAD 16
#define DHEAD 128
#define BATCH 2

#define NX   ((size_t)BATCH * SEQ * EMBED)   // 8388608
#define NW1  ((size_t)3 * EMBED * EMBED)     // 12582912
#define NB1  ((size_t)3 * EMBED)             // 6144
#define NW2  ((size_t)EMBED * EMBED)         // 4194304
#define NB2  ((size_t)EMBED)                 // 2048

typedef __bf16 bf16;
typedef __attribute__((__ext_vector_type__(8))) __bf16 bf16x8;
typedef __attribute__((__ext_vector_type__(4))) __bf16 bf16x4;
typedef __attribute__((__ext_vector_type__(4))) float f32x4;
typedef __attribute__((__ext_vector_type__(4))) unsigned int u32x4;

#define NEG_BIG (-1.0e30f)

__device__ __forceinline__ f32x4 mfma_16x16x32(bf16x8 a, bf16x8 b, f32x4 c) {
  return __builtin_amdgcn_mfma_f32_16x16x32_bf16(a, b, c, 0, 0, 0);
}

// async global->LDS, 16B per lane; dst is wave-uniform base, lane i lands at
// dst + i*16B (m97-verified pattern)
__device__ __forceinline__ void llds16(bf16* dst, const bf16* src) {
  __builtin_amdgcn_global_load_lds(
      (const __attribute__((address_space(1))) void*)src,
      (__attribute__((address_space(3))) void*)dst, 16, 0, 0);
}

// raw barrier: no vmcnt drain (unlike __syncthreads) -- keeps staging loads
// in flight across phases (T4). Memory clobbers pin LDS/global ops.
#define BAR()                                   \
  {                                             \
    asm volatile("" ::: "memory");              \
    __builtin_amdgcn_s_barrier();               \
    asm volatile("" ::: "memory");              \
  }

// ---------------------------------------------------------------------------
// Input normalization: detect fp32 vs bf16 storage, convert to bf16 ws.
// ---------------------------------------------------------------------------
__global__ void convert_inputs(const void* __restrict__ xin,
                               const void* __restrict__ w1in,
                               const void* __restrict__ b1in,
                               const void* __restrict__ w2in,
                               const void* __restrict__ b2in,
                               bf16* __restrict__ xb, bf16* __restrict__ w1b,
                               bf16* __restrict__ b1b, bf16* __restrict__ w2b,
                               bf16* __restrict__ b2b, int* __restrict__ flagp)
{
  __shared__ int sflag;
  if (threadIdx.x == 0) sflag = 0;
  __syncthreads();
  const unsigned short* xh = (const unsigned short*)xin;
  int huge = 0;
  for (int i = threadIdx.x; i < 2048; i += 256) {
    float f = __uint_as_float((unsigned int)xh[i] << 16);
    if (!(fabsf(f) <= 1e4f)) huge = 1;  // catches NaN/Inf too
  }
  if (huge) sflag = 1;
  __syncthreads();
  const int isf32 = sflag;
  if (blockIdx.x == 0 && threadIdx.x == 0) *flagp = isf32;

  const void* srcs[5] = {xin, w1in, b1in, w2in, b2in};
  bf16* dsts[5] = {xb, w1b, b1b, w2b, b2b};
  const size_t lens[5] = {NX, NW1, NB1, NW2, NB2};
  const size_t gid = (size_t)blockIdx.x * blockDim.x + threadIdx.x;
  const size_t gstride = (size_t)gridDim.x * blockDim.x;
  for (int sidx = 0; sidx < 5; ++sidx) {
    const size_t n8 = lens[sidx] >> 3;
    bf16* d = dsts[sidx];
    if (isf32) {
      const float* s = (const float*)srcs[sidx];
      for (size_t i = gid; i < n8; i += gstride) {
        const float* sp = s + i * 8;
        bf16x8 r;
#pragma unroll
        for (int j = 0; j < 8; ++j) r[j] = (bf16)sp[j];
        *(bf16x8*)(d + i * 8) = r;
      }
    } else {
      const u32x4* s = (const u32x4*)srcs[sidx];
      for (size_t i = gid; i < n8; i += gstride)
        *(u32x4*)(d + i * 8) = s[i];
    }
  }
}

// ---------------------------------------------------------------------------
// NT GEMM, phase-pipelined (T3+T4+T5): C[M,N] = A[M,K]*B[N,K]^T + bias[N]
// BM=128, BN=256, BK=32; 512 threads = 8 waves (2M x 4N), 64x64 out/wave.
// LDS: ring of 4 K-tile slots (A 8KiB + B 16KiB each) = 96 KiB, 1 block/CU.
// Per phase (= per K-tile t):
//   stage tile t+3 into slot (t+3)&3 (3 x global_load_lds dwordx4/thread)
//   8 x ds_read_b128 (A 4 + B 4 frags, XOR-swizzled: conflict-free)
//   s_barrier ; setprio(1) ; 16 MFMA ; setprio(0)
//   s_waitcnt vmcnt(6)  <- counted: 2 stage-units in flight, never 0 mid-loop
//   s_barrier
// Staging legality: slot (t+3)&3 == slot (t-1)&3, whose reads drained at
// phase t-1's final barrier. Landing: wait at phase t guarantees tile t+1
// (staged at t-2; exactly stages t-1,t = 6 loads are newer).
// Swizzle (rule #21, both-sides): phys granule = logical ^ (row&3); staging
// pre-swizzles the per-lane GLOBAL address, LDS dst stays linear.
// MODE 0: QKV epilogue -> q [BH,S,Dh], k [BH,S,Dh], v^T [BH,Dh,S]
// MODE 1: plain epilogue -> out[M, 2048], dtype per *flagp
// ---------------------------------------------------------------------------
#define GSTAGE(tt)                                                       \
  {                                                                      \
    const int _slot = (tt) & 3;                                          \
    const int _k0 = (tt) << 5;                                           \
    _Pragma("unroll") for (int j = 0; j < 3; ++j)                        \
        llds16(&sAB[_slot][dstofs[j]], srcbase[j] + _k0);                \
  }

template <int MODE>
__global__ __launch_bounds__(512, 1) void gemm_nt2(
    const bf16* __restrict__ A, const bf16* __restrict__ B,
    const bf16* __restrict__ bias, int K,
    void* __restrict__ out0v, bf16* __restrict__ out1, bf16* __restrict__ out2,
    const int* __restrict__ flagp)
{
  __shared__ __align__(16) bf16 sAB[4][12288];  // slot: A[0,4096) B[4096,12288)
  const int t = threadIdx.x;
  const int lane = t & 63, w = t >> 6;
  const int wm = w >> 2, wn = w & 3;        // wm 0..1 (M), wn 0..3 (N)
  const int lr = lane & 15, lq = lane >> 4;
  const int m0 = blockIdx.y * 128, n0 = blockIdx.x * 256;
  const int NT = K >> 5;                    // 64

  // staging geometry: 24 wave-calls of 1024B (A: 0..7, B: 8..23), 3/wave.
  // within a call: lane -> row lane>>2 (of 16), phys granule lane&3;
  // logical (global) granule = phys ^ (row&3)  [2-bit XOR swizzle]
  const int srow = lane >> 2;
  const int glog = (lane & 3) ^ (srow & 3);
  const bf16* srcbase[3];
  int dstofs[3];
#pragma unroll
  for (int j = 0; j < 3; ++j) {
    const int c2 = w * 3 + j;
    if (c2 < 8) {  // A rows m0 + c2*16 + srow
      srcbase[j] = A + (size_t)(m0 + c2 * 16 + srow) * K + glog * 8;
      dstofs[j] = c2 * 512;
    } else {       // B rows n0 + (c2-8)*16 + srow
      const int b = c2 - 8;
      srcbase[j] = B + (size_t)(n0 + b * 16 + srow) * K + glog * 8;
      dstofs[j] = 4096 + b * 512;
    }
  }

  f32x4 acc[4][4];
#pragma unroll
  for (int i = 0; i < 4; ++i)
#pragma unroll
    for (int j = 0; j < 4; ++j) acc[i][j] = (f32x4){0.f, 0.f, 0.f, 0.f};

  // ds_read addressing: row*32 elems + swizzled granule
  const int rdg = ((lq ^ (lr & 3)) << 3);
  const int aofs = (wm * 64 + lr) * 32 + rdg;
  const int bofs = 4096 + (wn * 64 + lr) * 32 + rdg;

  // prologue: stage tiles 0,1,2 (9 loads/thread); tile 0 landed at vmcnt(6)
  GSTAGE(0);
  GSTAGE(1);
  GSTAGE(2);
  asm volatile("s_waitcnt vmcnt(6)" ::: "memory");
  BAR();

  for (int tt = 0; tt < NT; ++tt) {
    const bf16* sl = sAB[tt & 3];
    if (tt + 3 < NT) GSTAGE(tt + 3);
    bf16x8 af[4], bfr[4];
#pragma unroll
    for (int i = 0; i < 4; ++i) {
      af[i]  = *(const bf16x8*)(sl + aofs + i * 512);
      bfr[i] = *(const bf16x8*)(sl + bofs + i * 512);
    }
    BAR();
    __builtin_amdgcn_s_setprio(1);
#pragma unroll
    for (int mi = 0; mi < 4; ++mi)
#pragma unroll
      for (int ni = 0; ni < 4; ++ni)
        acc[mi][ni] = mfma_16x16x32(af[mi], bfr[ni], acc[mi][ni]);
    __builtin_amdgcn_s_setprio(0);
    if (tt <= NT - 4)      { asm volatile("s_waitcnt vmcnt(6)" ::: "memory"); }
    else if (tt == NT - 3) { asm volatile("s_waitcnt vmcnt(3)" ::: "memory"); }
    else if (tt == NT - 2) { asm volatile("s_waitcnt vmcnt(0)" ::: "memory"); }
    BAR();
  }

  // epilogue: C/D layout row = wm*64 + mi*16 + lq*4 + reg (M),
  //           col = wn*64 + ni*16 + lr (N)
  if (MODE == 0) {
    const int which = n0 >> 11;
    const int bb = m0 >> 11;
    const int s0 = m0 & 2047;
    if (which == 2) {
      // V transposed: [BH, Dh, S]; 4 regs = 4 consecutive s -> 8B store
      bf16* dst = out2;
#pragma unroll
      for (int ni = 0; ni < 4; ++ni) {
        const int ng = n0 + wn * 64 + ni * 16 + lr;
        const int h = (ng >> 7) & 15;
        const int d = ng & 127;
        const float bv = (float)bias[ng];
        bf16* rowp =
            dst + ((size_t)(bb * NHEAD + h) * DHEAD + d) * SEQ + s0 + wm * 64;
#pragma unroll
        for (int mi = 0; mi < 4; ++mi) {
          bf16x4 pk;
#pragma unroll
          for (int reg = 0; reg < 4; ++reg)
            pk[reg] = (bf16)(acc[mi][ni][reg] + bv);
          *(bf16x4*)(rowp + mi * 16 + lq * 4) = pk;
        }
      }
    } else {
      bf16* dst = (which == 0) ? (bf16*)out0v : out1;
#pragma unroll
      for (int ni = 0; ni < 4; ++ni) {
        const int ng = n0 + wn * 64 + ni * 16 + lr;
        const int h = (ng >> 7) & 15;
        const int d = ng & 127;
        const float bv = (float)bias[ng];
        bf16* hb = dst + (size_t)(bb * NHEAD + h) * SEQ * DHEAD + d;
#pragma unroll
        for (int mi = 0; mi < 4; ++mi)
#pragma unroll
          for (int reg = 0; reg < 4; ++reg) {
            const int s = s0 + wm * 64 + mi * 16 + lq * 4 + reg;
            hb[(size_t)s * DHEAD] = (bf16)(acc[mi][ni][reg] + bv);
          }
      }
    }
  } else {
    const int isf32 = *flagp;
#pragma unroll
    for (int ni = 0; ni < 4; ++ni) {
      const int col = n0 + wn * 64 + ni * 16 + lr;
      const float bv = (float)bias[col];
#pragma unroll
      for (int mi = 0; mi < 4; ++mi)
#pragma unroll
        for (int reg = 0; reg < 4; ++reg) {
          const int row = m0 + wm * 64 + mi * 16 + lq * 4 + reg;
          const float v = acc[mi][ni][reg] + bv;
          const size_t idx = (size_t)row * EMBED + col;
          if (isf32) ((float*)out0v)[idx] = v;
          else       ((bf16*)out0v)[idx] = (bf16)v;
        }
    }
  }
}

// ---------------------------------------------------------------------------
// Causal flash attention, pair-balanced: block (bh, p) handles q-tiles
// {p, 31-p} (64 rows each) over the shared K range kt=0..31-p.
// Swapped-operand form: S^T = mfma(K,Q); lane owns one q-row; P via
// XOR-swizzled packed ds_write_b64; PV computes O^T = V^T * P^T.
// ---------------------------------------------------------------------------
__device__ __forceinline__ void qk_softmax_tile(
    const bf16* __restrict__ sK, bf16* __restrict__ sP, const bf16x8* aq,
    float& m_i, float& l_i, f32x4* oacc, int kt, int qt,
    int w, int lr, int lq, int sPofs)
{
  const float scale = 0.08838834764831845f;  // 1/sqrt(128)
  f32x4 tacc[4];
#pragma unroll
  for (int ni = 0; ni < 4; ++ni) tacc[ni] = (f32x4){0.f, 0.f, 0.f, 0.f};
#pragma unroll
  for (int ks = 0; ks < 4; ++ks)
#pragma unroll
    for (int ni = 0; ni < 4; ++ni) {
      bf16x8 bk = *(const bf16x8*)(sK + (ni * 16 + lr) * 136 + ks * 32 + lq * 8);
      tacc[ni] = mfma_16x16x32(bk, aq[ks], tacc[ni]);
    }
  float pp[4][4];
  const int qg = qt * 64 + w * 16 + lr;
#pragma unroll
  for (int ni = 0; ni < 4; ++ni)
#pragma unroll
    for (int reg = 0; reg < 4; ++reg) {
      float sv = tacc[ni][reg] * scale;
      if (kt == qt) {
        const int kg = kt * 64 + ni * 16 + lq * 4 + reg;
        if (kg > qg) sv = NEG_BIG;
      }
      pp[ni][reg] = sv;
    }
  float mx;
  {
    float a0 = fmaxf(fmaxf(pp[0][0], pp[0][1]), fmaxf(pp[0][2], pp[0][3]));
    float a1 = fmaxf(fmaxf(pp[1][0], pp[1][1]), fmaxf(pp[1][2], pp[1][3]));
    float a2 = fmaxf(fmaxf(pp[2][0], pp[2][1]), fmaxf(pp[2][2], pp[2][3]));
    float a3 = fmaxf(fmaxf(pp[3][0], pp[3][1]), fmaxf(pp[3][2], pp[3][3]));
    mx = fmaxf(fmaxf(a0, a1), fmaxf(a2, a3));
  }
  mx = fmaxf(mx, __shfl_xor(mx, 16, 64));
  mx = fmaxf(mx, __shfl_xor(mx, 32, 64));
  const float mnew = fmaxf(m_i, mx);
  const float alpha = __expf(m_i - mnew);
  float ls = 0.f;
#pragma unroll
  for (int ni = 0; ni < 4; ++ni) {
    float s0 = __expf(pp[ni][0] - mnew);
    float s1 = __expf(pp[ni][1] - mnew);
    float s2 = __expf(pp[ni][2] - mnew);
    float s3 = __expf(pp[ni][3] - mnew);
    pp[ni][0] = s0; pp[ni][1] = s1; pp[ni][2] = s2; pp[ni][3] = s3;
    ls += (s0 + s1) + (s2 + s3);
  }
  ls += __shfl_xor(ls, 16, 64);
  ls += __shfl_xor(ls, 32, 64);
  l_i = l_i * alpha + ls;
  m_i = mnew;
#pragma unroll
  for (int dt = 0; dt < 8; ++dt) oacc[dt] *= alpha;
  bf16* rowp = sP + (sPofs + w * 16 + lr) * 64;
  const int swz = lr & 7;
#pragma unroll
  for (int ni = 0; ni < 4; ++ni) {
    bf16x4 pk;
#pragma unroll
    for (int reg = 0; reg < 4; ++reg) pk[reg] = (bf16)pp[ni][reg];
    const int col = ni * 16 + lq * 4;
    const int scol = (((col >> 3) ^ swz) << 3) | (col & 7);
    *(bf16x4*)(rowp + scol) = pk;
  }
}

__device__ __forceinline__ void pv_tile(const bf16* __restrict__ sP,
                                        const bf16* __restrict__ sV,
                                        f32x4* oacc, int w, int lr, int lq,
                                        int sPofs)
{
  const bf16* rowp = sP + (sPofs + w * 16 + lr) * 64;
  const int swz = lr & 7;
#pragma unroll
  for (int ks2 = 0; ks2 < 2; ++ks2) {
    const int chunk = ks2 * 4 + lq;
    bf16x8 bp = *(const bf16x8*)(rowp + ((chunk ^ swz) << 3));
#pragma unroll
    for (int dt = 0; dt < 8; ++dt) {
      bf16x8 av =
          *(const bf16x8*)(sV + (dt * 16 + lr) * 72 + ks2 * 32 + lq * 8);
      oacc[dt] = mfma_16x16x32(av, bp, oacc[dt]);
    }
  }
}

__global__ __launch_bounds__(256, 2) void attn_fwd(
    const bf16* __restrict__ qb, const bf16* __restrict__ kb,
    const bf16* __restrict__ vt, bf16* __restrict__ aout)
{
  __shared__ bf16 sK[64 * 136];    // [k][d], +8 pad
  __shared__ bf16 sV[128 * 72];    // [d][k], +8 pad
  __shared__ bf16 sP[128 * 64];    // [q][k] XOR-swizzled
  const int t = threadIdx.x;
  const int lane = t & 63, w = t >> 6;
  const int lr = lane & 15, lq = lane >> 4;
  const int p  = blockIdx.x & 15;
  const int bh = blockIdx.x >> 4;
  const int bb = bh >> 4, h = bh & 15;
  const int qlo = p, qhi = 31 - p;

  bf16x8 aqL[4], aqH[4];
  {
    const bf16* qpL =
        qb + ((size_t)bh * SEQ + qlo * 64 + w * 16 + lr) * DHEAD + lq * 8;
    const bf16* qpH =
        qb + ((size_t)bh * SEQ + qhi * 64 + w * 16 + lr) * DHEAD + lq * 8;
#pragma unroll
    for (int ks = 0; ks < 4; ++ks) {
      aqL[ks] = *(const bf16x8*)(qpL + ks * 32);
      aqH[ks] = *(const bf16x8*)(qpH + ks * 32);
    }
  }

  f32x4 oL[8], oH[8];
#pragma unroll
  for (int i = 0; i < 8; ++i) {
    oL[i] = (f32x4){0.f, 0.f, 0.f, 0.f};
    oH[i] = (f32x4){0.f, 0.f, 0.f, 0.f};
  }
  float mL = NEG_BIG, mH = NEG_BIG;
  float lL = 0.f, lH = 0.f;

  bf16x8 rk[4], rv[4];
  const int kr_ = t >> 4, kd_ = t & 15;
  const int vr_ = t >> 3, vk_ = t & 7;
#define FETCH(ktv)                                                          \
  {                                                                         \
    const int _kt = (ktv);                                                  \
    _Pragma("unroll") for (int i = 0; i < 4; ++i) {                         \
      rk[i] = *(const bf16x8*)(kb + ((size_t)bh * SEQ + _kt * 64 +          \
                                     (i * 16 + kr_)) * DHEAD + kd_ * 8);    \
      rv[i] = *(const bf16x8*)(vt + ((size_t)bh * DHEAD + (i * 32 + vr_)) * \
                                     SEQ + _kt * 64 + vk_ * 8);             \
    }                                                                       \
  }
#define COMMIT()                                                            \
  {                                                                         \
    _Pragma("unroll") for (int i = 0; i < 4; ++i) {                         \
      *(bf16x8*)(sK + (i * 16 + kr_) * 136 + kd_ * 8) = rk[i];              \
      *(bf16x8*)(sV + (i * 32 + vr_) * 72 + vk_ * 8) = rv[i];               \
    }                                                                       \
  }

  FETCH(0);
  COMMIT();
  __syncthreads();

  for (int kt = 0; kt <= qhi; ++kt) {
    if (kt < qhi) FETCH(kt + 1);
    const bool doLo = (kt <= qlo);

    qk_softmax_tile(sK, sP, aqH, mH, lH, oH, kt, qhi, w, lr, lq, 64);
    if (doLo) qk_softmax_tile(sK, sP, aqL, mL, lL, oL, kt, qlo, w, lr, lq, 0);
    asm volatile("s_waitcnt lgkmcnt(0)" ::: "memory");
    pv_tile(sP, sV, oH, w, lr, lq, 64);
    if (doLo) pv_tile(sP, sV, oL, w, lr, lq, 0);

    __syncthreads();
    if (kt < qhi) {
      COMMIT();
      __syncthreads();
    }
  }

#pragma unroll
  for (int side = 0; side < 2; ++side) {
    const f32x4* oacc = side ? oH : oL;
    const float linv = 1.0f / (side ? lH : lL);
    const int qt = side ? qhi : qlo;
    const int qg = qt * 64 + w * 16 + lr;
    bf16* outp = aout + ((size_t)bb * SEQ + qg) * EMBED + h * 128 + lq * 4;
#pragma unroll
    for (int dt = 0; dt < 8; ++dt) {
      bf16x4 pk;
#pragma unroll
      for (int reg = 0; reg < 4; ++reg)
        pk[reg] = (bf16)(oacc[dt][reg] * linv);
      *(bf16x4*)(outp + dt * 16) = pk;
    }
  }
#undef FETCH
#undef COMMIT
}

extern "C" void kernel_launch(void* const* d_in, const int* in_sizes, int n_in,
                              void* d_out, int out_size, void* d_ws, size_t ws_size,
                              hipStream_t stream) {
  const void* x    = d_in[0];
  const void* Wqkv = d_in[1];
  const void* bqkv = d_in[2];
  const void* Wout = d_in[3];
  const void* bout = d_in[4];

  int* flagp = (int*)d_ws;
  bf16* base = (bf16*)((char*)d_ws + 256);
  bf16* xb   = base;
  bf16* w1b  = xb + NX;
  bf16* b1b  = w1b + NW1;
  bf16* w2b  = b1b + NB1;
  bf16* b2b  = w2b + NW2;
  bf16* qb   = b2b + NB2;
  bf16* kb   = qb + NX;
  bf16* vt   = kb + NX;
  bf16* aout = vt + NX;

  convert_inputs<<<dim3(1024), dim3(256), 0, stream>>>(
      x, Wqkv, bqkv, Wout, bout, xb, w1b, b1b, w2b, b2b, flagp);
  // QKV projection: M=4096, N=6144, K=2048 -> 768 blocks (3 full CU waves)
  gemm_nt2<0><<<dim3(24, 32), dim3(512), 0, stream>>>(
      xb, w1b, b1b, EMBED, (void*)qb, kb, vt, flagp);
  // attention: 32 bh * 16 balanced pairs
  attn_fwd<<<dim3(512), dim3(256), 0, stream>>>(qb, kb, vt, aout);
  // out projection: M=4096, N=2048, K=2048 -> 256 blocks (1 full CU wave)
  gemm_nt2<1><<<dim3(8, 32), dim3(512), 0, stream>>>(
      aout, w2b, b2b, EMBED, d_out, nullptr, nullptr, flagp);
}